// Round 2
// baseline (591.621 us; speedup 1.0000x reference)
//
#include <hip/hip_runtime.h>

#define BB 32
#define CC 3
#define LL 512
#define EE 512
// output offsets (floats)
#define O2_OFF ((size_t)BB*CC*LL*LL)         // 25165824
#define O3_OFF (O2_OFF + (size_t)BB*CC*LL*EE) // 50331648
// ws offsets (floats)
#define WS_H   0
#define WS_QX  49152
#define WS_QKV 98304
#define WS_W   147456

__device__ __forceinline__ float wred_sum(float v){
#pragma unroll
  for (int m = 32; m >= 1; m >>= 1) v += __shfl_xor(v, m, 64);
  return v;
}
__device__ __forceinline__ float wred_max(float v){
#pragma unroll
  for (int m = 32; m >= 1; m >>= 1) v = fmaxf(v, __shfl_xor(v, m, 64));
  return v;
}
__device__ __forceinline__ void f4ma(float4& a, float s, const float4& b){
  a.x = fmaf(s, b.x, a.x); a.y = fmaf(s, b.y, a.y);
  a.z = fmaf(s, b.z, a.z); a.w = fmaf(s, b.w, a.w);
}
__device__ __forceinline__ float4 f4sub(const float4& a, const float4& b){
  return make_float4(a.x-b.x, a.y-b.y, a.z-b.z, a.w-b.w);
}

// ---------------- Kernel 1: per-(b,c) precompute: h[e], w ----------------
// T0=t0@Tw, T1=t1@Tw, Q=(x0_last@Qw)*T0+Qb, K=(u0@Kw)*T1+Kb,
// gt = Q*K*T1,  h[e] = sum_f Vw[c,e,f]*gt[f],  w = sum(T0*T1)/sqrt(sum T0^2 + sum T1^2)
__global__ __launch_bounds__(512) void k1_precompute(
    const float* __restrict__ x0, const float* __restrict__ u0,
    const float* __restrict__ t0, const float* __restrict__ t1,
    const float* __restrict__ Qw, const float* __restrict__ Qb,
    const float* __restrict__ Vw,
    const float* __restrict__ Kw, const float* __restrict__ Kb,
    const float* __restrict__ Tw,
    float* __restrict__ ws_h, float* __restrict__ ws_w)
{
  const int bc = blockIdx.x;
  const int b = bc / CC, c = bc % CC;
  const int tid = threadIdx.x;
  const int wid = tid >> 6, lane = tid & 63;
  __shared__ __align__(16) float t0v[EE], t1v[EE], xl[EE], uv[EE], gt[EE];
  __shared__ float red[3][8];

  t0v[tid] = t0[b*EE + tid];
  t1v[tid] = t1[b*EE + tid];
  xl[tid]  = x0[((size_t)bc*LL + (LL-1))*EE + tid];
  uv[tid]  = u0[(size_t)bc*EE + tid];
  __syncthreads();

  const int f = tid;
  const float* twp = Tw + (size_t)c*EE*EE + f;
  const float* qwp = Qw + (size_t)c*EE*EE + f;
  const float* kwp = Kw + (size_t)c*EE*EE + f;
  float aT0 = 0.f, aT1 = 0.f, aQ = 0.f, aK = 0.f;
  for (int e = 0; e < EE; ++e) {
    float wt = twp[(size_t)e*EE];
    aT0 = fmaf(t0v[e], wt, aT0);
    aT1 = fmaf(t1v[e], wt, aT1);
    aQ  = fmaf(xl[e],  qwp[(size_t)e*EE], aQ);
    aK  = fmaf(uv[e],  kwp[(size_t)e*EE], aK);
  }
  float Qv = aQ*aT0 + Qb[c*EE + f];
  float Kv = aK*aT1 + Kb[c*EE + f];
  float g  = Qv*Kv;
  gt[f] = g*aT1;

  float pn = wred_sum(aT0*aT1);
  float p0 = wred_sum(aT0*aT0);
  float p1 = wred_sum(aT1*aT1);
  if (lane == 0) { red[0][wid]=pn; red[1][wid]=p0; red[2][wid]=p1; }
  __syncthreads();
  if (tid == 0) {
    float sn=0.f, s0=0.f, s1=0.f;
    for (int i=0;i<8;++i){ sn+=red[0][i]; s0+=red[1][i]; s1+=red[2][i]; }
    ws_w[bc] = sn / sqrtf(s0 + s1);
  }
  // h[r] = Vw[c,r,:] . gt   (rows split over 8 waves, lanes over f)
  const float4 g0 = *reinterpret_cast<const float4*>(&gt[lane*8]);
  const float4 g1 = *reinterpret_cast<const float4*>(&gt[lane*8+4]);
  for (int r = wid; r < EE; r += 8) {
    const float4* vr = reinterpret_cast<const float4*>(Vw + ((size_t)c*EE + r)*EE);
    float4 v0 = vr[lane*2], v1 = vr[lane*2+1];
    float acc = v0.x*g0.x + v0.y*g0.y + v0.z*g0.z + v0.w*g0.w
              + v1.x*g1.x + v1.y*g1.y + v1.z*g1.z + v1.w*g1.w;
    acc = wred_sum(acc);
    if (lane == 0) ws_h[(size_t)bc*EE + r] = acc;
  }
}

// ------- Kernel 2: per-(b,c): s=x0@h, softmax->QKV, qx, y rows, out3 -------
// mean(x1', axis=L) telescopes: mean = (y[511] - y[0] + qx)/512
__global__ __launch_bounds__(512) void k2_softmax_stats(
    const float* __restrict__ A0, const float* __restrict__ x0,
    const float* __restrict__ u0,
    const float* __restrict__ ws_h, const float* __restrict__ ws_w,
    float* __restrict__ ws_qx, float* __restrict__ ws_qkv,
    float* __restrict__ out3)
{
  const int bc = blockIdx.x;
  const int tid = threadIdx.x;
  const int wid = tid >> 6, lane = tid & 63;
  __shared__ __align__(16) float hb[EE], sb[LL];
  __shared__ __align__(16) float a0r0[LL], a0r3[LL];
  __shared__ float red[8];
  const size_t abase = (size_t)bc*LL*LL;
  const size_t xbase = (size_t)bc*LL*EE;

  hb[tid]   = ws_h[(size_t)bc*EE + tid];
  a0r0[tid] = A0[abase + tid];
  a0r3[tid] = A0[abase + (size_t)(LL-1)*LL + tid];
  __syncthreads();

  // pass A: s[l] = x0[l,:] . h
  const float4 h0 = *reinterpret_cast<const float4*>(&hb[lane*8]);
  const float4 h1 = *reinterpret_cast<const float4*>(&hb[lane*8+4]);
  for (int l = wid; l < LL; l += 8) {
    const float4* xr = reinterpret_cast<const float4*>(x0 + xbase + (size_t)l*EE);
    float4 v0 = xr[lane*2], v1 = xr[lane*2+1];
    float acc = v0.x*h0.x + v0.y*h0.y + v0.z*h0.z + v0.w*h0.w
              + v1.x*h1.x + v1.y*h1.y + v1.z*h1.z + v1.w*h1.w;
    acc = wred_sum(acc);
    if (lane == 0) sb[l] = acc;
  }
  __syncthreads();

  // softmax over sb[0..511]
  float v = sb[tid];
  float mx = wred_max(v);
  if (lane == 0) red[wid] = mx;
  __syncthreads();
  mx = red[0];
#pragma unroll
  for (int i = 1; i < 8; ++i) mx = fmaxf(mx, red[i]);
  float ev = __expf(v - mx);
  float sm = wred_sum(ev);
  __syncthreads();
  if (lane == 0) red[wid] = sm;
  __syncthreads();
  float tot = 0.f;
#pragma unroll
  for (int i = 0; i < 8; ++i) tot += red[i];
  float qk = ev / tot;
  sb[tid] = qk;
  ws_qkv[(size_t)bc*LL + tid] = qk;
  __syncthreads();

  // pass B: columns e=tid; qx, y[0], y[L-1]
  float qx=0.f, y0=0.f, y3=0.f;
  for (int m = 0; m < LL; ++m) {
    float xm = x0[xbase + (size_t)m*EE + tid];
    qx = fmaf(sb[m],   xm, qx);
    y0 = fmaf(a0r0[m], xm, y0);
    y3 = fmaf(a0r3[m], xm, y3);
  }
  ws_qx[(size_t)bc*EE + tid] = qx;
  float wv = ws_w[bc];
  float mean = (y3 - y0 + qx) * (1.f/(float)LL);
  out3[(size_t)bc*EE + tid] = wv * (mean - u0[(size_t)bc*EE + tid]);
}

// ---- Kernel 3: out2 rows 0..510 = (A0[l+1]-A0[l]) @ x0 - x0[l];
//                row 511 = qx - x0[511] (acc discarded). 128x128x32 tile. ----
#define TM 128
#define TN 128
#define TK 32
__global__ __launch_bounds__(256) void k3_gemm(
    const float* __restrict__ A0, const float* __restrict__ x0,
    const float* __restrict__ ws_qx, float* __restrict__ out2)
{
  const int bc = blockIdx.y;
  const int rt = blockIdx.x >> 2;
  const int nt = blockIdx.x & 3;
  const int r0 = rt * TM, n0 = nt * TN;
  const int tid = threadIdx.x;
  const int tx = tid & 15, ty = tid >> 4;
  __shared__ __align__(16) float As[TK][132];   // k-major, 129 rows used
  __shared__ __align__(16) float Bs[TK][TN];
  const size_t abase = (size_t)bc*LL*LL;
  const size_t xbase = (size_t)bc*LL*EE;

  float4 acc[8][2];
#pragma unroll
  for (int j = 0; j < 8; ++j) { acc[j][0] = make_float4(0,0,0,0); acc[j][1] = make_float4(0,0,0,0); }

  for (int k0 = 0; k0 < LL; k0 += TK) {
    __syncthreads();
    // stage A rows r0..r0+128 (129 rows), cols k0..k0+31; row 512 -> copy row 511 (don't-care)
    for (int idx = tid; idx < 129*8; idx += 256) {
      int i = idx >> 3, kq = idx & 7;
      int gr = r0 + i;
      if (gr > LL-1) gr = LL-1;  // local diff for last row becomes 0; epilogue discards it
      float4 va = *reinterpret_cast<const float4*>(A0 + abase + (size_t)gr*LL + k0 + kq*4);
      As[kq*4+0][i] = va.x; As[kq*4+1][i] = va.y;
      As[kq*4+2][i] = va.z; As[kq*4+3][i] = va.w;
    }
    // stage B: 32 k-rows x 128 cols
    for (int idx = tid; idx < 32*32; idx += 256) {
      int kk = idx >> 5, jq = idx & 31;
      *reinterpret_cast<float4*>(&Bs[kk][jq*4]) =
          *reinterpret_cast<const float4*>(x0 + xbase + (size_t)(k0+kk)*EE + n0 + jq*4);
    }
    __syncthreads();
#pragma unroll 2
    for (int k = 0; k < TK; ++k) {
      const float4* As4k = reinterpret_cast<const float4*>(&As[k][0]);
      const float4* Bs4k = reinterpret_cast<const float4*>(&Bs[k][0]);
      float4 b0 = Bs4k[tx], b1 = Bs4k[tx+16];
      float4 a0v = As4k[ty*2], a1v = As4k[ty*2+1];
      float alast = As[k][ty*8+8];
      float d[8];
      d[0]=a0v.y-a0v.x; d[1]=a0v.z-a0v.y; d[2]=a0v.w-a0v.z; d[3]=a1v.x-a0v.w;
      d[4]=a1v.y-a1v.x; d[5]=a1v.z-a1v.y; d[6]=a1v.w-a1v.z; d[7]=alast-a1v.w;
#pragma unroll
      for (int j = 0; j < 8; ++j) { f4ma(acc[j][0], d[j], b0); f4ma(acc[j][1], d[j], b1); }
    }
  }
  // epilogue: out2 = acc - x0; global row 511 = qx - x0 (acc discarded)
#pragma unroll
  for (int j = 0; j < 8; ++j) {
    int gr = r0 + ty*8 + j;
#pragma unroll
    for (int h = 0; h < 2; ++h) {
      int col = n0 + tx*4 + h*64;
      float4 xv = *reinterpret_cast<const float4*>(x0 + xbase + (size_t)gr*EE + col);
      float4 o;
      if (gr == LL-1) {
        float4 qv = *reinterpret_cast<const float4*>(ws_qx + (size_t)bc*EE + col);
        o = f4sub(qv, xv);
      } else {
        o = f4sub(acc[j][h], xv);
      }
      *reinterpret_cast<float4*>(out2 + xbase + (size_t)gr*EE + col) = o;
    }
  }
}

// ---- Kernel 4: out1[l] = A0[l+1]-A0[0]-A0[l] (l<511), QKV-A0[0] (l=511) ----
__global__ __launch_bounds__(256) void k4_out1(
    const float* __restrict__ A0, const float* __restrict__ ws_qkv,
    float* __restrict__ out1)
{
  const int bc = blockIdx.y;
  const int r0 = blockIdx.x * 32;
  const int tid = threadIdx.x;
  const size_t abase = (size_t)bc*LL*LL;
#pragma unroll 4
  for (int p = 0; p < 16; ++p) {
    int idx = p*256 + tid;
    int row = r0 + (idx >> 7);
    int col = (idx & 127) * 4;
    float4 a0z = *reinterpret_cast<const float4*>(A0 + abase + col);
    float4 o;
    if (row < LL-1) {
      float4 an = *reinterpret_cast<const float4*>(A0 + abase + (size_t)(row+1)*LL + col);
      float4 ac = *reinterpret_cast<const float4*>(A0 + abase + (size_t)row*LL + col);
      o = f4sub(f4sub(an, a0z), ac);
    } else {
      float4 qv = *reinterpret_cast<const float4*>(ws_qkv + (size_t)bc*LL + col);
      o = f4sub(qv, a0z);
    }
    *reinterpret_cast<float4*>(out1 + abase + (size_t)row*LL + col) = o;
  }
}

extern "C" void kernel_launch(void* const* d_in, const int* in_sizes, int n_in,
                              void* d_out, int out_size, void* d_ws, size_t ws_size,
                              hipStream_t stream)
{
  const float* A0 = (const float*)d_in[0];
  const float* x0 = (const float*)d_in[1];
  const float* u0 = (const float*)d_in[2];
  const float* t0 = (const float*)d_in[3];
  const float* t1 = (const float*)d_in[4];
  const float* Qw = (const float*)d_in[5];
  const float* Qb = (const float*)d_in[6];
  const float* Vw = (const float*)d_in[7];
  // d_in[8] = V_bias: per-(b,c) constant in s -> softmax-invariant; skipped.
  const float* Kw = (const float*)d_in[9];
  const float* Kb = (const float*)d_in[10];
  const float* Tw = (const float*)d_in[11];
  // d_in[12] = T_bias: unused by the reference.

  float* ws     = (float*)d_ws;
  float* ws_h   = ws + WS_H;
  float* ws_qx  = ws + WS_QX;
  float* ws_qkv = ws + WS_QKV;
  float* ws_w   = ws + WS_W;

  float* out1 = (float*)d_out;
  float* out2 = out1 + O2_OFF;
  float* out3 = out1 + O3_OFF;

  k1_precompute<<<BB*CC, 512, 0, stream>>>(x0, u0, t0, t1, Qw, Qb, Vw, Kw, Kb, Tw, ws_h, ws_w);
  k2_softmax_stats<<<BB*CC, 512, 0, stream>>>(A0, x0, u0, ws_h, ws_w, ws_qx, ws_qkv, out3);
  k3_gemm<<<dim3(16, BB*CC), 256, 0, stream>>>(A0, x0, ws_qx, out2);
  k4_out1<<<dim3(16, BB*CC), 256, 0, stream>>>(A0, ws_qkv, out1);
}

// Round 3
// 402.714 us; speedup vs baseline: 1.4691x; 1.4691x over previous
//
#include <hip/hip_runtime.h>

#define BB 32
#define CC 3
#define LL 512
#define EE 512
// output offsets (floats)
#define O2_OFF ((size_t)BB*CC*LL*LL)          // 25165824
#define O3_OFF (O2_OFF + (size_t)BB*CC*LL*EE) // 50331648

typedef short bf16x8 __attribute__((ext_vector_type(8)));
typedef float f32x4  __attribute__((ext_vector_type(4)));

__device__ __forceinline__ float wred_sum(float v){
#pragma unroll
  for (int m = 32; m >= 1; m >>= 1) v += __shfl_xor(v, m, 64);
  return v;
}
__device__ __forceinline__ float wred_max(float v){
#pragma unroll
  for (int m = 32; m >= 1; m >>= 1) v = fmaxf(v, __shfl_xor(v, m, 64));
  return v;
}
// f32 -> bf16 round-to-nearest-even
__device__ __forceinline__ unsigned short f2bf(float x){
  unsigned u = __float_as_uint(x);
  return (unsigned short)((u + 0x7FFFu + ((u >> 16) & 1u)) >> 16);
}

// ============ Kernel A: fused precompute + softmax/stats + out3 + out1 row 511 ============
// Phase 1 (per bc): T0=t0@Tw, T1=t1@Tw, Q=(x0_last@Qw)*T0+Qb, K=(u0@Kw)*T1+Kb,
//   gt=Q*K*T1, h=Vw@gt, w=sum(T0*T1)/sqrt(sum T0^2+sum T1^2)
// Phase 2: s=x0@h -> softmax -> QKV; qx=QKV@x0; y0,y3 matvecs;
//   out3 = w*((y3-y0+qx)/512 - u0); out1[511] = QKV - A0[0]
__global__ __launch_bounds__(512) void kA_fused(
    const float* __restrict__ A0, const float* __restrict__ x0,
    const float* __restrict__ u0,
    const float* __restrict__ t0, const float* __restrict__ t1,
    const float* __restrict__ Qw, const float* __restrict__ Qb,
    const float* __restrict__ Vw,
    const float* __restrict__ Kw, const float* __restrict__ Kb,
    const float* __restrict__ Tw,
    float* __restrict__ ws_qx, float* __restrict__ out1, float* __restrict__ out3)
{
  const int bc = blockIdx.x;
  const int b = bc / CC, c = bc % CC;
  const int tid = threadIdx.x;
  const int wid = tid >> 6, lane = tid & 63;
  __shared__ __align__(16) float t0v[EE], t1v[EE], xl[EE], uv[EE], gt[EE];
  __shared__ __align__(16) float hb[EE], sb[LL], a0r0[LL], a0r3[LL];
  __shared__ float red[3][8];
  __shared__ float wsh;
  const size_t abase = (size_t)bc*LL*LL;
  const size_t xbase = (size_t)bc*LL*EE;

  t0v[tid] = t0[b*EE + tid];
  t1v[tid] = t1[b*EE + tid];
  xl[tid]  = x0[xbase + (size_t)(LL-1)*EE + tid];
  uv[tid]  = u0[(size_t)bc*EE + tid];
  a0r0[tid] = A0[abase + tid];
  a0r3[tid] = A0[abase + (size_t)(LL-1)*LL + tid];
  __syncthreads();

  // ---- phase 1: four fused mat-vecs along columns ----
  const int f = tid;
  const float* twp = Tw + (size_t)c*EE*EE + f;
  const float* qwp = Qw + (size_t)c*EE*EE + f;
  const float* kwp = Kw + (size_t)c*EE*EE + f;
  float aT0 = 0.f, aT1 = 0.f, aQ = 0.f, aK = 0.f;
  for (int e = 0; e < EE; ++e) {
    float wt = twp[(size_t)e*EE];
    aT0 = fmaf(t0v[e], wt, aT0);
    aT1 = fmaf(t1v[e], wt, aT1);
    aQ  = fmaf(xl[e],  qwp[(size_t)e*EE], aQ);
    aK  = fmaf(uv[e],  kwp[(size_t)e*EE], aK);
  }
  float Qv = aQ*aT0 + Qb[c*EE + f];
  float Kv = aK*aT1 + Kb[c*EE + f];
  gt[f] = Qv*Kv*aT1;

  float pn = wred_sum(aT0*aT1);
  float p0 = wred_sum(aT0*aT0);
  float p1 = wred_sum(aT1*aT1);
  if (lane == 0) { red[0][wid]=pn; red[1][wid]=p0; red[2][wid]=p1; }
  __syncthreads();
  if (tid == 0) {
    float sn=0.f, s0=0.f, s1=0.f;
    for (int i=0;i<8;++i){ sn+=red[0][i]; s0+=red[1][i]; s1+=red[2][i]; }
    wsh = sn / sqrtf(s0 + s1);
  }
  // h[r] = Vw[c,r,:] . gt
  {
    const float4 g0 = *reinterpret_cast<const float4*>(&gt[lane*8]);
    const float4 g1 = *reinterpret_cast<const float4*>(&gt[lane*8+4]);
    for (int r = wid; r < EE; r += 8) {
      const float4* vr = reinterpret_cast<const float4*>(Vw + ((size_t)c*EE + r)*EE);
      float4 v0 = vr[lane*2], v1 = vr[lane*2+1];
      float acc = v0.x*g0.x + v0.y*g0.y + v0.z*g0.z + v0.w*g0.w
                + v1.x*g1.x + v1.y*g1.y + v1.z*g1.z + v1.w*g1.w;
      acc = wred_sum(acc);
      if (lane == 0) hb[r] = acc;
    }
  }
  __syncthreads();

  // ---- phase 2a: s[l] = x0[l,:].h ----
  {
    const float4 h0 = *reinterpret_cast<const float4*>(&hb[lane*8]);
    const float4 h1 = *reinterpret_cast<const float4*>(&hb[lane*8+4]);
    for (int l = wid; l < LL; l += 8) {
      const float4* xr = reinterpret_cast<const float4*>(x0 + xbase + (size_t)l*EE);
      float4 v0 = xr[lane*2], v1 = xr[lane*2+1];
      float acc = v0.x*h0.x + v0.y*h0.y + v0.z*h0.z + v0.w*h0.w
                + v1.x*h1.x + v1.y*h1.y + v1.z*h1.z + v1.w*h1.w;
      acc = wred_sum(acc);
      if (lane == 0) sb[l] = acc;
    }
  }
  __syncthreads();

  // ---- softmax ----
  float v = sb[tid];
  float mx = wred_max(v);
  if (lane == 0) red[0][wid] = mx;
  __syncthreads();
  mx = red[0][0];
#pragma unroll
  for (int i = 1; i < 8; ++i) mx = fmaxf(mx, red[0][i]);
  float ev = __expf(v - mx);
  float sm = wred_sum(ev);
  __syncthreads();
  if (lane == 0) red[0][wid] = sm;
  __syncthreads();
  float tot = 0.f;
#pragma unroll
  for (int i = 0; i < 8; ++i) tot += red[0][i];
  float qk = ev / tot;
  sb[tid] = qk;
  // out1 last row: QKV - A0[:, :, 0, :]
  out1[abase + (size_t)(LL-1)*LL + tid] = qk - a0r0[tid];
  __syncthreads();

  // ---- phase 2b: columns e=tid; qx, y0, y3, out3 ----
  float qx=0.f, y0=0.f, y3=0.f;
  for (int m = 0; m < LL; ++m) {
    float xm = x0[xbase + (size_t)m*EE + tid];
    qx = fmaf(sb[m],   xm, qx);
    y0 = fmaf(a0r0[m], xm, y0);
    y3 = fmaf(a0r3[m], xm, y3);
  }
  ws_qx[(size_t)bc*EE + tid] = qx;
  float mean = (y3 - y0 + qx) * (1.f/(float)LL);
  out3[(size_t)bc*EE + tid] = wsh * (mean - uv[tid]);
}

// ============ Kernel 3: bf16 MFMA GEMM ============
// out2 rows 0..510 = (A0[l+1]-A0[l]) @ x0 - x0[l]  (bf16 MFMA, f32 acc)
// out2 row 511     = qx - x0[511]                   (exact f32)
// out1 rows 0..510 = A0[l+1]-A0[0]-A0[l]            (written by nt==0 blocks, f32)
// Tile 128x128, BK=32, 4 waves, mfma_f32_16x16x32_bf16.
// LDS: A row-major [128][k], B transposed [n][k]; row stride 80B (64B data+16B pad)
// -> 2-way bank aliasing only (free). B k-slot XOR-swizzled by ((n>>2)&3)<<4 to
// kill transpose-write conflicts; reads apply the same XOR.
#define ASTR 80
__global__ __launch_bounds__(256) void k3_mfma(
    const float* __restrict__ A0, const float* __restrict__ x0,
    const float* __restrict__ ws_qx,
    float* __restrict__ out1, float* __restrict__ out2)
{
  const int bc = blockIdx.y;
  const int rt = blockIdx.x >> 2, nt = blockIdx.x & 3;
  const int r0 = rt*128, n0b = nt*128;
  const int t = threadIdx.x;
  const int lane = t & 63, wid = t >> 6;
  const int wr = wid >> 1, wc = wid & 1;
  __shared__ __align__(16) char As[128*ASTR];
  __shared__ __align__(16) char Bs[128*ASTR];
  const size_t abase = (size_t)bc*LL*LL;
  const size_t xbase = (size_t)bc*LL*EE;

  f32x4 acc[4][4];
#pragma unroll
  for (int mi=0; mi<4; ++mi)
#pragma unroll
    for (int ni=0; ni<4; ++ni)
      acc[mi][ni] = (f32x4){0.f,0.f,0.f,0.f};

  const int bkl = (t & 7) * 4;        // B: k low index (4 consecutive k per thread)
  const int bn0 = (t >> 3) * 4;       // B: 4 consecutive n per thread

  for (int k0 = 0; k0 < LL; k0 += 32) {
    __syncthreads();
    // ---- stage A (rows of D = A0[l+1]-A0[l]) + fused out1 store ----
#pragma unroll
    for (int i = 0; i < 4; ++i) {
      int idx = i*256 + t;
      int row = idx >> 3, kq = idx & 7;
      int gr = r0 + row;
      int gr1 = (gr+1 > LL-1) ? (LL-1) : (gr+1);
      float4 va = *reinterpret_cast<const float4*>(A0 + abase + (size_t)gr *LL + k0 + kq*4);
      float4 vb = *reinterpret_cast<const float4*>(A0 + abase + (size_t)gr1*LL + k0 + kq*4);
      ushort4 pk;
      pk.x = f2bf(vb.x - va.x); pk.y = f2bf(vb.y - va.y);
      pk.z = f2bf(vb.z - va.z); pk.w = f2bf(vb.w - va.w);
      *reinterpret_cast<ushort4*>(As + row*ASTR + kq*8) = pk;
      if (nt == 0 && gr < LL-1) {
        float4 az = *reinterpret_cast<const float4*>(A0 + abase + k0 + kq*4);
        float4 o = make_float4(vb.x - az.x - va.x, vb.y - az.y - va.y,
                               vb.z - az.z - va.z, vb.w - az.w - va.w);
        *reinterpret_cast<float4*>(out1 + abase + (size_t)gr*LL + k0 + kq*4) = o;
      }
    }
    // ---- stage B transposed: Bt[n][k] bf16, XOR-swizzled k slot ----
    {
      float xq[4][4];
#pragma unroll
      for (int i = 0; i < 4; ++i)
        *reinterpret_cast<float4*>(xq[i]) =
          *reinterpret_cast<const float4*>(x0 + xbase + (size_t)(k0+bkl+i)*EE + n0b + bn0);
#pragma unroll
      for (int j = 0; j < 4; ++j) {
        int n = bn0 + j;
        ushort4 pk;
        pk.x = f2bf(xq[0][j]); pk.y = f2bf(xq[1][j]);
        pk.z = f2bf(xq[2][j]); pk.w = f2bf(xq[3][j]);
        int kb = (bkl*2) ^ (((n >> 2) & 3) << 4);
        *reinterpret_cast<ushort4*>(Bs + n*ASTR + kb) = pk;
      }
    }
    __syncthreads();
    // ---- fragments + MFMA ----
    bf16x8 af[4], bf[4];
#pragma unroll
    for (int mi=0; mi<4; ++mi) {
      int row = wr*64 + mi*16 + (lane & 15);
      af[mi] = *reinterpret_cast<const bf16x8*>(As + row*ASTR + ((lane>>4)*16));
    }
#pragma unroll
    for (int ni=0; ni<4; ++ni) {
      int n = wc*64 + ni*16 + (lane & 15);
      int kb = ((lane>>4)*16) ^ (((n >> 2) & 3) << 4);
      bf[ni] = *reinterpret_cast<const bf16x8*>(Bs + n*ASTR + kb);
    }
#pragma unroll
    for (int mi=0; mi<4; ++mi)
#pragma unroll
      for (int ni=0; ni<4; ++ni)
        acc[mi][ni] = __builtin_amdgcn_mfma_f32_16x16x32_bf16(af[mi], bf[ni], acc[mi][ni], 0, 0, 0);
  }

  // ---- epilogue: out2 = acc - x0 ; row 511 = qx - x0 ----
#pragma unroll
  for (int mi=0; mi<4; ++mi) {
#pragma unroll
    for (int r=0; r<4; ++r) {
      int grow = r0 + wr*64 + mi*16 + (lane>>4)*4 + r;
      const size_t rowoff = xbase + (size_t)grow*EE;
#pragma unroll
      for (int ni=0; ni<4; ++ni) {
        int gcol = n0b + wc*64 + ni*16 + (lane & 15);
        float xv = x0[rowoff + gcol];
        float val;
        if (grow == LL-1) val = ws_qx[(size_t)bc*EE + gcol] - xv;
        else              val = acc[mi][ni][r] - xv;
        out2[rowoff + gcol] = val;
      }
    }
  }
}

extern "C" void kernel_launch(void* const* d_in, const int* in_sizes, int n_in,
                              void* d_out, int out_size, void* d_ws, size_t ws_size,
                              hipStream_t stream)
{
  const float* A0 = (const float*)d_in[0];
  const float* x0 = (const float*)d_in[1];
  const float* u0 = (const float*)d_in[2];
  const float* t0 = (const float*)d_in[3];
  const float* t1 = (const float*)d_in[4];
  const float* Qw = (const float*)d_in[5];
  const float* Qb = (const float*)d_in[6];
  const float* Vw = (const float*)d_in[7];
  // d_in[8] = V_bias: per-(b,c) constant in softmax logits -> invariant; skipped.
  const float* Kw = (const float*)d_in[9];
  const float* Kb = (const float*)d_in[10];
  const float* Tw = (const float*)d_in[11];
  // d_in[12] = T_bias: unused by the reference.

  float* ws_qx = (float*)d_ws;   // 96*512 floats

  float* out1 = (float*)d_out;
  float* out2 = out1 + O2_OFF;
  float* out3 = out1 + O3_OFF;

  kA_fused<<<BB*CC, 512, 0, stream>>>(A0, x0, u0, t0, t1, Qw, Qb, Vw, Kw, Kb, Tw,
                                      ws_qx, out1, out3);
  k3_mfma<<<dim3(16, BB*CC), 256, 0, stream>>>(A0, x0, ws_qx, out1, out2);
}

// Round 8
// 343.532 us; speedup vs baseline: 1.7222x; 1.1723x over previous
//
#include <hip/hip_runtime.h>
#include <stdint.h>

#define BB 32
#define CC 3
#define LL 512
#define EE 512
#define NBC (BB*CC)

// output offsets (floats)
#define O2_OFF ((size_t)NBC*LL*LL)
#define O3_OFF (O2_OFF + (size_t)NBC*LL*EE)

// ws layout (bytes): ws_qx at 0; fast-path extras beyond 512KB
#define WSB_ADIFF ((size_t)512*1024)
#define ADIFF_BYTES ((size_t)NBC*LL*LL*2)     // 48MiB
#define WSB_X0T   (WSB_ADIFF + ADIFF_BYTES)
#define WS_FAST_NEED (WSB_X0T + ADIFF_BYTES)  // ~96.5MB

typedef short bf16x8 __attribute__((ext_vector_type(8)));
typedef float f32x4  __attribute__((ext_vector_type(4)));

__device__ __forceinline__ float wred_sum(float v){
#pragma unroll
  for (int m = 32; m >= 1; m >>= 1) v += __shfl_xor(v, m, 64);
  return v;
}
__device__ __forceinline__ float wred_max(float v){
#pragma unroll
  for (int m = 32; m >= 1; m >>= 1) v = fmaxf(v, __shfl_xor(v, m, 64));
  return v;
}
__device__ __forceinline__ float4 f4sub(const float4& a, const float4& b){
  return make_float4(a.x-b.x, a.y-b.y, a.z-b.z, a.w-b.w);
}
__device__ __forceinline__ unsigned short f2bf(float x){
  unsigned u = __float_as_uint(x);
  return (unsigned short)((u + 0x7FFFu + ((u >> 16) & 1u)) >> 16);
}

// ============ kA_fused: R3-VERBATIM (proven pass) ============
__global__ __launch_bounds__(512) void kA_fused(
    const float* __restrict__ A0, const float* __restrict__ x0,
    const float* __restrict__ u0,
    const float* __restrict__ t0, const float* __restrict__ t1,
    const float* __restrict__ Qw, const float* __restrict__ Qb,
    const float* __restrict__ Vw,
    const float* __restrict__ Kw, const float* __restrict__ Kb,
    const float* __restrict__ Tw,
    float* __restrict__ ws_qx, float* __restrict__ out1, float* __restrict__ out3)
{
  const int bc = blockIdx.x;
  const int b = bc / CC, c = bc % CC;
  const int tid = threadIdx.x;
  const int wid = tid >> 6, lane = tid & 63;
  __shared__ __align__(16) float t0v[EE], t1v[EE], xl[EE], uv[EE], gt[EE];
  __shared__ __align__(16) float hb[EE], sb[LL], a0r0[LL], a0r3[LL];
  __shared__ float red[3][8];
  __shared__ float wsh;
  const size_t abase = (size_t)bc*LL*LL;
  const size_t xbase = (size_t)bc*LL*EE;

  t0v[tid] = t0[b*EE + tid];
  t1v[tid] = t1[b*EE + tid];
  xl[tid]  = x0[xbase + (size_t)(LL-1)*EE + tid];
  uv[tid]  = u0[(size_t)bc*EE + tid];
  a0r0[tid] = A0[abase + tid];
  a0r3[tid] = A0[abase + (size_t)(LL-1)*LL + tid];
  __syncthreads();

  const int f = tid;
  const float* twp = Tw + (size_t)c*EE*EE + f;
  const float* qwp = Qw + (size_t)c*EE*EE + f;
  const float* kwp = Kw + (size_t)c*EE*EE + f;
  float aT0 = 0.f, aT1 = 0.f, aQ = 0.f, aK = 0.f;
  for (int e = 0; e < EE; ++e) {
    float wt = twp[(size_t)e*EE];
    aT0 = fmaf(t0v[e], wt, aT0);
    aT1 = fmaf(t1v[e], wt, aT1);
    aQ  = fmaf(xl[e],  qwp[(size_t)e*EE], aQ);
    aK  = fmaf(uv[e],  kwp[(size_t)e*EE], aK);
  }
  float Qv = aQ*aT0 + Qb[c*EE + f];
  float Kv = aK*aT1 + Kb[c*EE + f];
  gt[f] = Qv*Kv*aT1;

  float pn = wred_sum(aT0*aT1);
  float p0 = wred_sum(aT0*aT0);
  float p1 = wred_sum(aT1*aT1);
  if (lane == 0) { red[0][wid]=pn; red[1][wid]=p0; red[2][wid]=p1; }
  __syncthreads();
  if (tid == 0) {
    float sn=0.f, s0=0.f, s1=0.f;
    for (int i=0;i<8;++i){ sn+=red[0][i]; s0+=red[1][i]; s1+=red[2][i]; }
    wsh = sn / sqrtf(s0 + s1);
  }
  {
    const float4 g0 = *reinterpret_cast<const float4*>(&gt[lane*8]);
    const float4 g1 = *reinterpret_cast<const float4*>(&gt[lane*8+4]);
    for (int r = wid; r < EE; r += 8) {
      const float4* vr = reinterpret_cast<const float4*>(Vw + ((size_t)c*EE + r)*EE);
      float4 v0 = vr[lane*2], v1 = vr[lane*2+1];
      float acc = v0.x*g0.x + v0.y*g0.y + v0.z*g0.z + v0.w*g0.w
                + v1.x*g1.x + v1.y*g1.y + v1.z*g1.z + v1.w*g1.w;
      acc = wred_sum(acc);
      if (lane == 0) hb[r] = acc;
    }
  }
  __syncthreads();

  {
    const float4 h0 = *reinterpret_cast<const float4*>(&hb[lane*8]);
    const float4 h1 = *reinterpret_cast<const float4*>(&hb[lane*8+4]);
    for (int l = wid; l < LL; l += 8) {
      const float4* xr = reinterpret_cast<const float4*>(x0 + xbase + (size_t)l*EE);
      float4 v0 = xr[lane*2], v1 = xr[lane*2+1];
      float acc = v0.x*h0.x + v0.y*h0.y + v0.z*h0.z + v0.w*h0.w
                + v1.x*h1.x + v1.y*h1.y + v1.z*h1.z + v1.w*h1.w;
      acc = wred_sum(acc);
      if (lane == 0) sb[l] = acc;
    }
  }
  __syncthreads();

  float v = sb[tid];
  float mx = wred_max(v);
  if (lane == 0) red[0][wid] = mx;
  __syncthreads();
  mx = red[0][0];
#pragma unroll
  for (int i = 1; i < 8; ++i) mx = fmaxf(mx, red[0][i]);
  float ev = __expf(v - mx);
  float sm = wred_sum(ev);
  __syncthreads();
  if (lane == 0) red[0][wid] = sm;
  __syncthreads();
  float tot = 0.f;
#pragma unroll
  for (int i = 0; i < 8; ++i) tot += red[0][i];
  float qk = ev / tot;
  sb[tid] = qk;
  out1[abase + (size_t)(LL-1)*LL + tid] = qk - a0r0[tid];
  __syncthreads();

  float qx=0.f, y0=0.f, y3=0.f;
  for (int m = 0; m < LL; ++m) {
    float xm = x0[xbase + (size_t)m*EE + tid];
    qx = fmaf(sb[m],   xm, qx);
    y0 = fmaf(a0r0[m], xm, y0);
    y3 = fmaf(a0r3[m], xm, y3);
  }
  ws_qx[(size_t)bc*EE + tid] = qx;
  float mean = (y3 - y0 + qx) * (1.f/(float)LL);
  out3[(size_t)bc*EE + tid] = wsh * (mean - uv[tid]);
}

// ============ k_conv2: PLAIN layouts (no swizzle, no fold) ============
// z==0: out1 rows 0..510 (verified logic from r4-r6) + adiff[gr][k] bf16
//       (pure diff; row 511 = zeros, epilogue overrides).
// z==1: x0t[e][m] bf16 plain row-major.
__global__ __launch_bounds__(512) void k_conv2(
    const float* __restrict__ A0, const float* __restrict__ x0,
    float* __restrict__ out1, char* __restrict__ adiff, char* __restrict__ x0t)
{
  const int bc = blockIdx.x;
  const int tile = blockIdx.y;   // 0..7
  const int t = threadIdx.x;
  if (blockIdx.z == 0) {
    const int r0 = tile*64;
    const size_t abase = (size_t)bc*LL*LL;
    char* ad = adiff + (size_t)bc*LL*LL*2;
    __shared__ __align__(16) float r0f[LL];
    r0f[t] = A0[abase + t];
    __syncthreads();
#pragma unroll 4
    for (int rep = 0; rep < 16; ++rep) {
      int pos = rep*512 + t;
      int rl = pos >> 7;
      int q  = pos & 127;
      int gr = r0 + rl;
      float4 d;
      if (gr < LL-1) {
        float4 a = *reinterpret_cast<const float4*>(A0 + abase + (size_t)gr*LL + q*4);
        float4 b = *reinterpret_cast<const float4*>(A0 + abase + (size_t)(gr+1)*LL + q*4);
        d = make_float4(b.x-a.x, b.y-a.y, b.z-a.z, b.w-a.w);
        float4 z = *reinterpret_cast<const float4*>(&r0f[q*4]);
        *reinterpret_cast<float4*>(out1 + abase + (size_t)gr*LL + q*4) = f4sub(d, z);
      } else {
        d = make_float4(0.f,0.f,0.f,0.f);   // row 511: GEMM acc discarded by epilogue
      }
      ushort4 pk;
      pk.x = f2bf(d.x); pk.y = f2bf(d.y); pk.z = f2bf(d.z); pk.w = f2bf(d.w);
      *reinterpret_cast<ushort4*>(ad + (size_t)gr*1024 + q*8) = pk;
    }
  } else {
    const int m0 = tile*64;
    const size_t xbase = (size_t)bc*LL*EE;
    char* xt = x0t + (size_t)bc*LL*EE*2;
    __shared__ float T[64][65];
    for (int ech = 0; ech < 8; ++ech) {
      const int e0 = ech*64;
      {
        int ml = t >> 3, seg = t & 7;
        const float* src = x0 + xbase + (size_t)(m0+ml)*EE + e0 + seg*8;
        float4 v0 = *reinterpret_cast<const float4*>(src);
        float4 v1 = *reinterpret_cast<const float4*>(src+4);
        T[ml][seg*8+0]=v0.x; T[ml][seg*8+1]=v0.y; T[ml][seg*8+2]=v0.z; T[ml][seg*8+3]=v0.w;
        T[ml][seg*8+4]=v1.x; T[ml][seg*8+5]=v1.y; T[ml][seg*8+6]=v1.z; T[ml][seg*8+7]=v1.w;
      }
      __syncthreads();
      {
        int el = t >> 3, c3 = t & 7;
        int eg = e0 + el;
        int mb = c3*8;
        ushort4 p0, p1;
        p0.x = f2bf(T[mb+0][el]); p0.y = f2bf(T[mb+1][el]);
        p0.z = f2bf(T[mb+2][el]); p0.w = f2bf(T[mb+3][el]);
        p1.x = f2bf(T[mb+4][el]); p1.y = f2bf(T[mb+5][el]);
        p1.z = f2bf(T[mb+6][el]); p1.w = f2bf(T[mb+7][el]);
        char* dst = xt + (size_t)eg*1024 + (size_t)(m0 + mb)*2;   // plain [e][m]
        *reinterpret_cast<ushort4*>(dst) = p0;
        *reinterpret_cast<ushort4*>(dst + 8) = p1;
      }
      __syncthreads();
    }
  }
}

// ============ k3_bf: r3's proven MFMA core, staging = plain bf16 copies ============
// LDS layouts, frag reads, MFMA order, epilogue: R3-VERBATIM.
#define ASTR 80
__global__ __launch_bounds__(256) void k3_bf(
    const char* __restrict__ adiff, const char* __restrict__ x0t,
    const float* __restrict__ x0, const float* __restrict__ ws_qx,
    float* __restrict__ out2)
{
  const int bc = blockIdx.y;
  const int rt = blockIdx.x >> 2, nt = blockIdx.x & 3;
  const int r0 = rt*128, n0b = nt*128;
  const int t = threadIdx.x;
  const int lane = t & 63, wid = t >> 6;
  const int wr = wid >> 1, wc = wid & 1;
  __shared__ __align__(16) char As[128*ASTR];
  __shared__ __align__(16) char Bs[128*ASTR];
  const char* ad = adiff + (size_t)bc*LL*LL*2;
  const char* xt = x0t  + (size_t)bc*LL*EE*2;
  const size_t xbase = (size_t)bc*LL*EE;
  f32x4 acc[4][4];
#pragma unroll
  for (int mi=0; mi<4; ++mi)
#pragma unroll
    for (int ni=0; ni<4; ++ni) acc[mi][ni] = (f32x4){0.f,0.f,0.f,0.f};

  for (int k0 = 0; k0 < LL; k0 += 32) {
    __syncthreads();
    // A: 128 rows x 4 chunks (16B = 8 k-values) of this k-slab
#pragma unroll
    for (int i = 0; i < 2; ++i) {
      int idx = i*256 + t;
      int row = idx >> 2, c = idx & 3;
      int4 v = *reinterpret_cast<const int4*>(ad + (size_t)(r0+row)*1024 + k0*2 + c*16);
      *reinterpret_cast<int4*>(As + row*ASTR + c*16) = v;
    }
    // B: 128 n-rows x 4 chunks, r3's n-XOR swizzle on the k-byte
#pragma unroll
    for (int i = 0; i < 2; ++i) {
      int idx = i*256 + t;
      int n = idx >> 2, c = idx & 3;
      int4 v = *reinterpret_cast<const int4*>(xt + (size_t)(n0b+n)*1024 + k0*2 + c*16);
      int kb = (c*16) ^ (((n >> 2) & 3) << 4);
      *reinterpret_cast<int4*>(Bs + n*ASTR + kb) = v;
    }
    __syncthreads();
    bf16x8 af[4], bfv[4];
#pragma unroll
    for (int mi=0; mi<4; ++mi) {
      int row = wr*64 + mi*16 + (lane & 15);
      af[mi] = *reinterpret_cast<const bf16x8*>(As + row*ASTR + ((lane>>4)*16));
    }
#pragma unroll
    for (int ni=0; ni<4; ++ni) {
      int n = wc*64 + ni*16 + (lane & 15);
      int kb = ((lane>>4)*16) ^ (((n >> 2) & 3) << 4);
      bfv[ni] = *reinterpret_cast<const bf16x8*>(Bs + n*ASTR + kb);
    }
#pragma unroll
    for (int mi=0; mi<4; ++mi)
#pragma unroll
      for (int ni=0; ni<4; ++ni)
        acc[mi][ni] = __builtin_amdgcn_mfma_f32_16x16x32_bf16(af[mi], bfv[ni], acc[mi][ni], 0, 0, 0);
  }
  // epilogue: R3-VERBATIM — out2 = acc - x0 (f32); row 511 = qx - x0
#pragma unroll
  for (int mi=0; mi<4; ++mi)
#pragma unroll
    for (int r=0; r<4; ++r) {
      int grow = r0 + wr*64 + mi*16 + (lane>>4)*4 + r;
      const size_t rowoff = xbase + (size_t)grow*EE;
#pragma unroll
      for (int ni=0; ni<4; ++ni) {
        int gcol = n0b + wc*64 + ni*16 + (lane & 15);
        float xv = x0[rowoff + gcol];
        float val;
        if (grow == LL-1) val = ws_qx[(size_t)bc*EE + gcol] - xv;
        else              val = acc[mi][ni][r] - xv;
        out2[rowoff + gcol] = val;
      }
    }
}

// ============ k3_mfma: R3-VERBATIM fallback (proven pass) ============
__global__ __launch_bounds__(256) void k3_mfma(
    const float* __restrict__ A0, const float* __restrict__ x0,
    const float* __restrict__ ws_qx,
    float* __restrict__ out1, float* __restrict__ out2)
{
  const int bc = blockIdx.y;
  const int rt = blockIdx.x >> 2, nt = blockIdx.x & 3;
  const int r0 = rt*128, n0b = nt*128;
  const int t = threadIdx.x;
  const int lane = t & 63, wid = t >> 6;
  const int wr = wid >> 1, wc = wid & 1;
  __shared__ __align__(16) char As[128*ASTR];
  __shared__ __align__(16) char Bs[128*ASTR];
  const size_t abase = (size_t)bc*LL*LL;
  const size_t xbase = (size_t)bc*LL*EE;
  f32x4 acc[4][4];
#pragma unroll
  for (int mi=0; mi<4; ++mi)
#pragma unroll
    for (int ni=0; ni<4; ++ni) acc[mi][ni] = (f32x4){0.f,0.f,0.f,0.f};
  const int bkl = (t & 7) * 4;
  const int bn0 = (t >> 3) * 4;
  for (int k0 = 0; k0 < LL; k0 += 32) {
    __syncthreads();
#pragma unroll
    for (int i = 0; i < 4; ++i) {
      int idx = i*256 + t;
      int row = idx >> 3, kq = idx & 7;
      int gr = r0 + row;
      int gr1 = (gr+1 > LL-1) ? (LL-1) : (gr+1);
      float4 va = *reinterpret_cast<const float4*>(A0 + abase + (size_t)gr *LL + k0 + kq*4);
      float4 vb = *reinterpret_cast<const float4*>(A0 + abase + (size_t)gr1*LL + k0 + kq*4);
      ushort4 pk;
      pk.x = f2bf(vb.x - va.x); pk.y = f2bf(vb.y - va.y);
      pk.z = f2bf(vb.z - va.z); pk.w = f2bf(vb.w - va.w);
      *reinterpret_cast<ushort4*>(As + row*ASTR + kq*8) = pk;
      if (nt == 0 && gr < LL-1) {
        float4 az = *reinterpret_cast<const float4*>(A0 + abase + k0 + kq*4);
        float4 o = make_float4(vb.x - az.x - va.x, vb.y - az.y - va.y,
                               vb.z - az.z - va.z, vb.w - az.w - va.w);
        *reinterpret_cast<float4*>(out1 + abase + (size_t)gr*LL + k0 + kq*4) = o;
      }
    }
    {
      float xq[4][4];
#pragma unroll
      for (int i = 0; i < 4; ++i)
        *reinterpret_cast<float4*>(xq[i]) =
          *reinterpret_cast<const float4*>(x0 + xbase + (size_t)(k0+bkl+i)*EE + n0b + bn0);
#pragma unroll
      for (int j = 0; j < 4; ++j) {
        int n = bn0 + j;
        ushort4 pk;
        pk.x = f2bf(xq[0][j]); pk.y = f2bf(xq[1][j]);
        pk.z = f2bf(xq[2][j]); pk.w = f2bf(xq[3][j]);
        int kb = (bkl*2) ^ (((n >> 2) & 3) << 4);
        *reinterpret_cast<ushort4*>(Bs + n*ASTR + kb) = pk;
      }
    }
    __syncthreads();
    bf16x8 af[4], bfv[4];
#pragma unroll
    for (int mi=0; mi<4; ++mi) {
      int row = wr*64 + mi*16 + (lane & 15);
      af[mi] = *reinterpret_cast<const bf16x8*>(As + row*ASTR + ((lane>>4)*16));
    }
#pragma unroll
    for (int ni=0; ni<4; ++ni) {
      int n = wc*64 + ni*16 + (lane & 15);
      int kb = ((lane>>4)*16) ^ (((n >> 2) & 3) << 4);
      bfv[ni] = *reinterpret_cast<const bf16x8*>(Bs + n*ASTR + kb);
    }
#pragma unroll
    for (int mi=0; mi<4; ++mi)
#pragma unroll
      for (int ni=0; ni<4; ++ni)
        acc[mi][ni] = __builtin_amdgcn_mfma_f32_16x16x32_bf16(af[mi], bfv[ni], acc[mi][ni], 0, 0, 0);
  }
#pragma unroll
  for (int mi=0; mi<4; ++mi)
#pragma unroll
    for (int r=0; r<4; ++r) {
      int grow = r0 + wr*64 + mi*16 + (lane>>4)*4 + r;
      const size_t rowoff = xbase + (size_t)grow*EE;
#pragma unroll
      for (int ni=0; ni<4; ++ni) {
        int gcol = n0b + wc*64 + ni*16 + (lane & 15);
        float xv = x0[rowoff + gcol];
        float val;
        if (grow == LL-1) val = ws_qx[(size_t)bc*EE + gcol] - xv;
        else              val = acc[mi][ni][r] - xv;
        out2[rowoff + gcol] = val;
      }
    }
}

extern "C" void kernel_launch(void* const* d_in, const int* in_sizes, int n_in,
                              void* d_out, int out_size, void* d_ws, size_t ws_size,
                              hipStream_t stream)
{
  const float* A0 = (const float*)d_in[0];
  const float* x0 = (const float*)d_in[1];
  const float* u0 = (const float*)d_in[2];
  const float* t0 = (const float*)d_in[3];
  const float* t1 = (const float*)d_in[4];
  const float* Qw = (const float*)d_in[5];
  const float* Qb = (const float*)d_in[6];
  const float* Vw = (const float*)d_in[7];
  // d_in[8] = V_bias: zeros + softmax-invariant; skipped.
  const float* Kw = (const float*)d_in[9];
  const float* Kb = (const float*)d_in[10];
  const float* Tw = (const float*)d_in[11];
  // d_in[12] = T_bias: unused by the reference.

  char*  wsb   = (char*)d_ws;
  float* ws_qx = (float*)wsb;

  float* out1 = (float*)d_out;
  float* out2 = out1 + O2_OFF;
  float* out3 = out1 + O3_OFF;

  const bool fast = ws_size >= WS_FAST_NEED;

  kA_fused<<<NBC, 512, 0, stream>>>(A0, x0, u0, t0, t1, Qw, Qb, Vw, Kw, Kb, Tw,
                                    ws_qx, out1, out3);
  if (fast) {
    char* adiff = wsb + WSB_ADIFF;
    char* x0t   = wsb + WSB_X0T;
    k_conv2<<<dim3(NBC, 8, 2), 512, 0, stream>>>(A0, x0, out1, adiff, x0t);
    k3_bf<<<dim3(16, NBC), 256, 0, stream>>>(adiff, x0t, x0, ws_qx, out2);
  } else {
    k3_mfma<<<dim3(16, NBC), 256, 0, stream>>>(A0, x0, ws_qx, out1, out2);
  }
}